// Round 13
// baseline (302.268 us; speedup 1.0000x reference)
//
#include <hip/hip_runtime.h>
#include <hip/hip_bf16.h>

#define BATCH   64
#define LEN     288
#define DIM     256
#define PAST    12
#define NWIN    (LEN - PAST)        // 276
#define M_DIM   (BATCH * NWIN)      // 17664
#define K_DIM   (PAST * DIM)        // 3072
#define N_DIM   3072

#define BM 256
#define BN 256
#define BK 64
#define NTILE   (K_DIM / BK)        // 48
#define NITER   (NTILE / 2)         // 24

#define GRID_N   12
#define BULK_WG  768                 // 64 bm x 12 bn = exactly 3 rounds @256 CU
#define TAIL_M0  16384
#define TAIL_QN  24
#define TAIL_WG  240                 // 10 x 24 quarter tiles (128x128)

typedef __attribute__((ext_vector_type(8))) short bh8;
typedef __attribute__((ext_vector_type(4))) float f32x4;

__device__ __forceinline__ void llds16(const void* g, void* l) {
    __builtin_amdgcn_global_load_lds(
        (const __attribute__((address_space(1))) unsigned int*)g,
        (__attribute__((address_space(3))) unsigned int*)l,
        16, 0, 0);
}

__global__ void cvt_both(const float* __restrict__ inA, const float* __restrict__ inW,
                         __hip_bfloat16* __restrict__ outA, __hip_bfloat16* __restrict__ outW,
                         int nA8, int nTot8) {
    int i = blockIdx.x * blockDim.x + threadIdx.x;
    if (i >= nTot8) return;
    const float* src;
    __hip_bfloat16* dst;
    int k;
    if (i < nA8) { src = inA; dst = outA; k = i; }
    else         { src = inW; dst = outW; k = i - nA8; }
    const float4* p = (const float4*)src;
    float4 a = p[2 * k], b = p[2 * k + 1];
    union { __hip_bfloat16 h[8]; int4 v; } u;
    u.h[0] = __float2bfloat16(a.x); u.h[1] = __float2bfloat16(a.y);
    u.h[2] = __float2bfloat16(a.z); u.h[3] = __float2bfloat16(a.w);
    u.h[4] = __float2bfloat16(b.x); u.h[5] = __float2bfloat16(b.y);
    u.h[6] = __float2bfloat16(b.z); u.h[7] = __float2bfloat16(b.w);
    ((int4*)dst)[k] = u.v;
}

// ONE barrier per interval (R12-proven wave-skew). SB0 around each barrier is
// LOAD-BEARING (R10: raw s_barrier is not a compiler memory fence).
#define SB0 __builtin_amdgcn_sched_barrier(0)
#define PH_MID  __builtin_amdgcn_s_setprio(1);
#define PH_END  __builtin_amdgcn_s_setprio(0); SB0; __builtin_amdgcn_s_barrier(); SB0;
#define PH_END_VM(N) __builtin_amdgcn_s_setprio(0); SB0; \
                asm volatile("s_waitcnt vmcnt(" #N ")" ::: "memory"); \
                __builtin_amdgcn_s_barrier(); SB0;

// ========== BULK: 256x256, 4 intervals/iter (2 per K-tile), 4 barriers/iter ==========
// Per iter (a=2i->buf0, b=2i+1->buf1, c=2i+2->buf0, d=2i+3->buf1):
//  J0: rd B(0) all(8) + A(0) mLo(8); stg b.Aq1,Aq3->buf1 | 32 MFMA mLo | barrier
//  J1: rd A(0) mHi(8);  stg c.B0-3, c.Aq0,Aq2 ->buf0     | 32 MFMA mHi | vmcnt(6); barrier
//  J2: rd B(1) all + A(1) mLo; stg c.Aq1,Aq3->buf0       | 32 MFMA mLo | barrier
//  J3: rd A(1) mHi;     stg d.B0-3, d.Aq0,Aq2 ->buf1     | 32 MFMA mHi | vmcnt(6); barrier
// WAR: every staged region's last read is in the PREVIOUS interval (reads complete
//  before their consuming MFMAs, which precede the interval-end barrier); stage
//  issues after that barrier. Audited per unit: J0 stages buf1.Aq1Aq3 (freed prev
//  J3); J1 stages buf0.B + buf0.Aq0Aq2 (freed J0); J2 stages buf0.Aq1Aq3 (freed
//  J1); J3 stages buf1.B + buf1.Aq0Aq2 (freed J2).
// RAW: at J1-end, in-flight = prevJ3(6)+J0(2)+J1(6)=14; vmcnt(6) drains 8 oldest
//  = ALL of tile b before J2/J3 read it. Symmetric at J3-end for tile c.
// Per-acc-cell accumulation order (k0 then k1 per K-tile) identical to R12.
#define LDS_A(buf) (smem + (buf) * 65536)
#define LDS_B(buf) (smem + (buf) * 65536 + 32768)

#define RD_BALL(buf) { \
    const char* _b = LDS_B(buf) + bRowB; \
    _Pragma("unroll") for (int ni = 0; ni < 4; ++ni) { \
        fb[ni][0] = *(const bh8*)(_b + ni * 2048 + kOff0); \
        fb[ni][1] = *(const bh8*)(_b + ni * 2048 + kOff1); \
    } }
#define RD_A4(buf, MB) { \
    const char* _b = LDS_A(buf) + aRowB; \
    _Pragma("unroll") for (int mi = 0; mi < 4; ++mi) { \
        a0[mi][0] = *(const bh8*)(_b + (MB + mi) * 2048 + kOff0); \
        a0[mi][1] = *(const bh8*)(_b + (MB + mi) * 2048 + kOff1); \
    } }
#define MFMA_H(MB) \
    _Pragma("unroll") for (int mi = 0; mi < 4; ++mi) \
    _Pragma("unroll") for (int ni = 0; ni < 4; ++ni) { \
        acc[(MB) + mi][ni] = __builtin_amdgcn_mfma_f32_16x16x32_bf16( \
            a0[mi][0], fb[ni][0], acc[(MB) + mi][ni], 0, 0, 0); \
        acc[(MB) + mi][ni] = __builtin_amdgcn_mfma_f32_16x16x32_bf16( \
            a0[mi][1], fb[ni][1], acc[(MB) + mi][ni], 0, 0, 0); \
    }
#define STG_A1(buf, kt, q) \
    llds16(Ag + aSrc[q] + (kt) * 64, LDS_A(buf) + (q) * 8192 + wOff);
#define STG_B1(buf, kt, u) \
    llds16(Wg + bSrc[u] + (kt) * 64, LDS_B(buf) + (u) * 8192 + wOff);

__global__ __launch_bounds__(512, 2)
void gemm_bulk(const __hip_bfloat16* __restrict__ Ag,
               const __hip_bfloat16* __restrict__ Wg,
               const float* __restrict__ bias,
               float* __restrict__ C)
{
    extern __shared__ char smem[];

    const int tid = threadIdx.x;
    const int wgid = (blockIdx.x & 7) * (BULK_WG / 8) + (blockIdx.x >> 3);
    const int bm = wgid / GRID_N;
    const int bn = wgid - bm * GRID_N;
    const int tile_m = bm * BM;
    const int tile_n = bn * BN;

    const int rd  = tid >> 3;
    const int chs = (((tid & 7) ^ (rd & 7)) * 8);
    int aSrc[4], bSrc[4];
#pragma unroll
    for (int rb = 0; rb < 4; ++rb) {
        int m  = tile_m + rb * 64 + rd;
        int bq = m / NWIN;
        int wq = m - bq * NWIN;
        aSrc[rb] = (bq * LEN + wq) * DIM + chs;          // window rows contiguous
        bSrc[rb] = (tile_n + rb * 64 + rd) * K_DIM + chs;
    }

    const int wave = tid >> 6, lane = tid & 63;
    const int wm = wave >> 2, wn = wave & 3;
    const int fr = lane & 15, kg = lane >> 4;
    const int sw    = (fr & 7) << 4;
    const int kOff0 = (kg * 16) ^ sw;
    const int kOff1 = kOff0 ^ 64;
    const int aRowB = (wm * 128 + fr) * 128;
    const int bRowB = (wn * 64 + fr) * 128;
    const int wOff  = wave * 1024;

    bh8 a0[4][2], fb[4][2];
    f32x4 acc[8][4] = {};

    // prologue: t0 all -> buf0 (8), t1.B + t1.Aq0,Aq2 -> buf1 (6)
    STG_B1(0, 0, 0); STG_B1(0, 0, 1); STG_B1(0, 0, 2); STG_B1(0, 0, 3);
    STG_A1(0, 0, 0); STG_A1(0, 0, 1); STG_A1(0, 0, 2); STG_A1(0, 0, 3);
    STG_B1(1, 1, 0); STG_B1(1, 1, 1); STG_B1(1, 1, 2); STG_B1(1, 1, 3);
    STG_A1(1, 1, 0); STG_A1(1, 1, 2);
    asm volatile("s_waitcnt vmcnt(6)" ::: "memory");     // t0 fully landed
    __builtin_amdgcn_s_barrier();
    SB0;

#pragma unroll 1
    for (int it = 0; it < NITER; ++it) {
        const int b = 2 * it + 1;
        int c = 2 * it + 2; if (c >= NTILE) c = NTILE - 2;   // same-bytes rewrite
        int d = 2 * it + 3; if (d >= NTILE) d = NTILE - 1;

        // J0
        RD_BALL(0); RD_A4(0, 0);
        STG_A1(1, b, 1); STG_A1(1, b, 3);
        PH_MID; MFMA_H(0); PH_END;

        // J1
        RD_A4(0, 4);
        STG_B1(0, c, 0); STG_B1(0, c, 1); STG_B1(0, c, 2); STG_B1(0, c, 3);
        STG_A1(0, c, 0); STG_A1(0, c, 2);
        PH_MID; MFMA_H(4); PH_END_VM(6);

        // J2
        RD_BALL(1); RD_A4(1, 0);
        STG_A1(0, c, 1); STG_A1(0, c, 3);
        PH_MID; MFMA_H(0); PH_END;

        // J3
        RD_A4(1, 4);
        STG_B1(1, d, 0); STG_B1(1, d, 1); STG_B1(1, d, 2); STG_B1(1, d, 3);
        STG_A1(1, d, 0); STG_A1(1, d, 2);
        PH_MID; MFMA_H(4); PH_END_VM(6);
    }

    float bv[4];
    const float* bp = bias + tile_n + wn * 64 + fr;
#pragma unroll
    for (int ni = 0; ni < 4; ++ni) bv[ni] = bp[ni * 16];

    const int r0 = (lane >> 4) * 4;
#pragma unroll
    for (int mi = 0; mi < 8; ++mi) {
#pragma unroll
        for (int j = 0; j < 4; ++j) {
            long m = tile_m + wm * 128 + mi * 16 + r0 + j;
            float* crow = C + m * (long)N_DIM + tile_n + wn * 64 + fr;
#pragma unroll
            for (int ni = 0; ni < 4; ++ni)
                __builtin_nontemporal_store(acc[mi][ni][j] + bv[ni], &crow[ni * 16]);
        }
    }
}

// ============================ TAIL: 128x128, 16x16x32 (R12-proven) ============================
#define TLDS_A(buf) (smem + (buf) * 32768)
#define TLDS_B(buf) (smem + (buf) * 32768 + 16384)

#define T_RD(buf) { \
    const char* _bb = TLDS_B(buf) + bRowB; \
    _Pragma("unroll") for (int ni = 0; ni < 2; ++ni) { \
        fb0[ni][0] = *(const bh8*)(_bb + ni * 2048 + kOff0); \
        fb0[ni][1] = *(const bh8*)(_bb + ni * 2048 + kOff1); \
    } \
    const char* _a = TLDS_A(buf) + aRowB; \
    _Pragma("unroll") for (int mi = 0; mi < 4; ++mi) { \
        a0[mi][0] = *(const bh8*)(_a + mi * 2048 + kOff0); \
        a0[mi][1] = *(const bh8*)(_a + mi * 2048 + kOff1); \
    } }
#define T_MFMA(MB) \
    _Pragma("unroll") for (int mi = 0; mi < 2; ++mi) \
    _Pragma("unroll") for (int ni = 0; ni < 2; ++ni) { \
        acc[MB + mi][ni] = __builtin_amdgcn_mfma_f32_16x16x32_bf16( \
            a0[MB + mi][0], fb0[ni][0], acc[MB + mi][ni], 0, 0, 0); \
        acc[MB + mi][ni] = __builtin_amdgcn_mfma_f32_16x16x32_bf16( \
            a0[MB + mi][1], fb0[ni][1], acc[MB + mi][ni], 0, 0, 0); \
    }
#define T_STG_A(buf, kt, u) \
    llds16(Ag + aSrc[u] + (kt) * 64, TLDS_A(buf) + (u) * 8192 + wOff);
#define T_STG_B(buf, kt, u) \
    llds16(Wg + bSrc[u] + (kt) * 64, TLDS_B(buf) + (u) * 8192 + wOff);

__global__ __launch_bounds__(512, 2)
void gemm_tail(const __hip_bfloat16* __restrict__ Ag,
               const __hip_bfloat16* __restrict__ Wg,
               const float* __restrict__ bias,
               float* __restrict__ C)
{
    extern __shared__ char smem[];

    const int tid = threadIdx.x;
    const int wgid = (blockIdx.x & 7) * (TAIL_WG / 8) + (blockIdx.x >> 3);
    const int qm = wgid / TAIL_QN;
    const int qn = wgid - qm * TAIL_QN;
    const int tile_m = TAIL_M0 + qm * 128;
    const int tile_n = qn * 128;

    const int rd  = tid >> 3;
    const int chs = (((tid & 7) ^ (rd & 7)) * 8);
    int aSrc[2], bSrc[2];
#pragma unroll
    for (int rb = 0; rb < 2; ++rb) {
        int m  = tile_m + rb * 64 + rd;
        int bq = m / NWIN;
        int wq = m - bq * NWIN;
        aSrc[rb] = (bq * LEN + wq) * DIM + chs;
        bSrc[rb] = (tile_n + rb * 64 + rd) * K_DIM + chs;
    }

    const int wave = tid >> 6, lane = tid & 63;
    const int wm = wave >> 2, wn = wave & 3;             // per-wave 64x32
    const int fr = lane & 15, kg = lane >> 4;
    const int sw    = (fr & 7) << 4;
    const int kOff0 = (kg * 16) ^ sw;
    const int kOff1 = kOff0 ^ 64;
    const int aRowB = (wm * 64 + fr) * 128;
    const int bRowB = (wn * 32 + fr) * 128;
    const int wOff  = wave * 1024;

    bh8 a0[4][2], fb0[2][2];
    f32x4 acc[4][2] = {};

    T_STG_A(0, 0, 0); T_STG_A(0, 0, 1); T_STG_B(0, 0, 0); T_STG_B(0, 0, 1);
    T_STG_A(1, 1, 0); T_STG_A(1, 1, 1);
    asm volatile("s_waitcnt vmcnt(2)" ::: "memory");
    __builtin_amdgcn_s_barrier();
    SB0;

#pragma unroll 1
    for (int it = 0; it < NITER; ++it) {
        const int b = 2 * it + 1;
        int c = 2 * it + 2; if (c >= NTILE) c = NTILE - 2;
        int d = 2 * it + 3; if (d >= NTILE) d = NTILE - 1;

        T_RD(0);
        T_STG_B(1, b, 0); T_STG_B(1, b, 1);
        PH_MID; T_MFMA(0); PH_END;

        T_STG_A(0, c, 0); T_STG_A(0, c, 1);
        PH_MID; T_MFMA(2); PH_END_VM(2);

        T_RD(1);
        T_STG_B(0, c, 0); T_STG_B(0, c, 1);
        PH_MID; T_MFMA(0); PH_END;

        T_STG_A(1, d, 0); T_STG_A(1, d, 1);
        PH_MID; T_MFMA(2); PH_END_VM(2);
    }

    float bv[2];
    const float* bp = bias + tile_n + wn * 32 + fr;
#pragma unroll
    for (int ni = 0; ni < 2; ++ni) bv[ni] = bp[ni * 16];

    const int r0 = (lane >> 4) * 4;
#pragma unroll
    for (int mi = 0; mi < 4; ++mi) {
#pragma unroll
        for (int j = 0; j < 4; ++j) {
            long m = tile_m + wm * 64 + mi * 16 + r0 + j;
            float* crow = C + m * (long)N_DIM + tile_n + wn * 32 + fr;
#pragma unroll
            for (int ni = 0; ni < 2; ++ni)
                __builtin_nontemporal_store(acc[mi][ni][j] + bv[ni], &crow[ni * 16]);
        }
    }
}

extern "C" void kernel_launch(void* const* d_in, const int* in_sizes, int n_in,
                              void* d_out, int out_size, void* d_ws, size_t ws_size,
                              hipStream_t stream) {
    const float* inp  = (const float*)d_in[0];
    const float* Wf   = (const float*)d_in[1];
    const float* bias = (const float*)d_in[2];
    float* out = (float*)d_out;

    __hip_bfloat16* Abf = (__hip_bfloat16*)d_ws;
    __hip_bfloat16* Wbf = (__hip_bfloat16*)((char*)d_ws + (size_t)BATCH * LEN * DIM * 2);

    const int nA8 = BATCH * LEN * DIM / 8;   // 589824
    const int nW8 = N_DIM * K_DIM / 8;       // 1179648
    const int nT8 = nA8 + nW8;
    cvt_both<<<(nT8 + 255) / 256, 256, 0, stream>>>(inp, Wf, Abf, Wbf, nA8, nT8);

    hipFuncSetAttribute((const void*)gemm_bulk,
                        hipFuncAttributeMaxDynamicSharedMemorySize, 131072);
    hipFuncSetAttribute((const void*)gemm_tail,
                        hipFuncAttributeMaxDynamicSharedMemorySize, 65536);
    gemm_bulk<<<dim3(BULK_WG), 512, 131072, stream>>>(Abf, Wbf, bias, out);
    gemm_tail<<<dim3(TAIL_WG), 512, 65536, stream>>>(Abf, Wbf, bias, out);
}

// Round 14
// 302.083 us; speedup vs baseline: 1.0006x; 1.0006x over previous
//
#include <hip/hip_runtime.h>
#include <hip/hip_bf16.h>

#define BATCH   64
#define LEN     288
#define DIM     256
#define PAST    12
#define NWIN    (LEN - PAST)        // 276
#define M_DIM   (BATCH * NWIN)      // 17664
#define K_DIM   (PAST * DIM)        // 3072
#define N_DIM   3072

#define BM 256
#define BN 256
#define BK 64
#define NTILE   (K_DIM / BK)        // 48
#define NITER   (NTILE / 2)         // 24

#define GRID_N   12
#define BULK_WG  768                 // 64 bm x 12 bn = exactly 3 rounds @256 CU
#define TAIL_M0  16384
#define TAIL_QN  24
#define TAIL_WG  240                 // 10 x 24 quarter tiles (128x128)

typedef __attribute__((ext_vector_type(8))) short bh8;
typedef __attribute__((ext_vector_type(4))) float f32x4;

__device__ __forceinline__ void llds16(const void* g, void* l) {
    __builtin_amdgcn_global_load_lds(
        (const __attribute__((address_space(1))) unsigned int*)g,
        (__attribute__((address_space(3))) unsigned int*)l,
        16, 0, 0);
}

__global__ void cvt_both(const float* __restrict__ inA, const float* __restrict__ inW,
                         __hip_bfloat16* __restrict__ outA, __hip_bfloat16* __restrict__ outW,
                         int nA8, int nTot8) {
    int i = blockIdx.x * blockDim.x + threadIdx.x;
    if (i >= nTot8) return;
    const float* src;
    __hip_bfloat16* dst;
    int k;
    if (i < nA8) { src = inA; dst = outA; k = i; }
    else         { src = inW; dst = outW; k = i - nA8; }
    const float4* p = (const float4*)src;
    float4 a = p[2 * k], b = p[2 * k + 1];
    union { __hip_bfloat16 h[8]; int4 v; } u;
    u.h[0] = __float2bfloat16(a.x); u.h[1] = __float2bfloat16(a.y);
    u.h[2] = __float2bfloat16(a.z); u.h[3] = __float2bfloat16(a.w);
    u.h[4] = __float2bfloat16(b.x); u.h[5] = __float2bfloat16(b.y);
    u.h[6] = __float2bfloat16(b.z); u.h[7] = __float2bfloat16(b.w);
    ((int4*)dst)[k] = u.v;
}

// R12 schedule, NO setprio: T5 is negative on non-drain-disciplined GEMM
// structures (m190). Prio-1 MFMA waves starve prio-0 read-issuing waves of
// issue slots, suppressing the wave-skew MFMA||LDS overlap R12 unlocked.
// SB0 around each barrier remains LOAD-BEARING (R10: raw s_barrier is not a
// compiler memory fence).
#define SB0 __builtin_amdgcn_sched_barrier(0)
#define PH_END  SB0; __builtin_amdgcn_s_barrier(); SB0;
#define PH_END_VM(N) SB0; \
                asm volatile("s_waitcnt vmcnt(" #N ")" ::: "memory"); \
                __builtin_amdgcn_s_barrier(); SB0;

// ============================ BULK: 256x256, 16x16x32 ============================
#define LDS_A(buf) (smem + (buf) * 65536)
#define LDS_B(buf) (smem + (buf) * 65536 + 32768)

#define RD_A4(buf, MB) { \
    const char* _b = LDS_A(buf) + aRowB; \
    _Pragma("unroll") for (int mi = 0; mi < 4; ++mi) { \
        a0[mi][0] = *(const bh8*)(_b + (MB + mi) * 2048 + kOff0); \
        a0[mi][1] = *(const bh8*)(_b + (MB + mi) * 2048 + kOff1); \
    } }
#define RD_B2(buf, dst, NB) { \
    const char* _b = LDS_B(buf) + bRowB; \
    _Pragma("unroll") for (int ni = 0; ni < 2; ++ni) { \
        dst[ni][0] = *(const bh8*)(_b + (NB + ni) * 2048 + kOff0); \
        dst[ni][1] = *(const bh8*)(_b + (NB + ni) * 2048 + kOff1); \
    } }
#define MFMA_Q(MB, NB, BB) \
    _Pragma("unroll") for (int mi = 0; mi < 4; ++mi) \
    _Pragma("unroll") for (int ni = 0; ni < 2; ++ni) { \
        acc[MB + mi][NB + ni] = __builtin_amdgcn_mfma_f32_16x16x32_bf16( \
            a0[mi][0], BB[ni][0], acc[MB + mi][NB + ni], 0, 0, 0); \
        acc[MB + mi][NB + ni] = __builtin_amdgcn_mfma_f32_16x16x32_bf16( \
            a0[mi][1], BB[ni][1], acc[MB + mi][NB + ni], 0, 0, 0); \
    }
#define STG_A1(buf, kt, q) \
    llds16(Ag + aSrc[q] + (kt) * 64, LDS_A(buf) + (q) * 8192 + wOff);
#define STG_B1(buf, kt, u) \
    llds16(Wg + bSrc[u] + (kt) * 64, LDS_B(buf) + (u) * 8192 + wOff);

__global__ __launch_bounds__(512, 2)
void gemm_bulk(const __hip_bfloat16* __restrict__ Ag,
               const __hip_bfloat16* __restrict__ Wg,
               const float* __restrict__ bias,
               float* __restrict__ C)
{
    extern __shared__ char smem[];

    const int tid = threadIdx.x;
    const int wgid = (blockIdx.x & 7) * (BULK_WG / 8) + (blockIdx.x >> 3);
    const int bm = wgid / GRID_N;
    const int bn = wgid - bm * GRID_N;
    const int tile_m = bm * BM;
    const int tile_n = bn * BN;

    const int rd  = tid >> 3;
    const int chs = (((tid & 7) ^ (rd & 7)) * 8);
    int aSrc[4], bSrc[4];
#pragma unroll
    for (int rb = 0; rb < 4; ++rb) {
        int m  = tile_m + rb * 64 + rd;
        int bq = m / NWIN;
        int wq = m - bq * NWIN;
        aSrc[rb] = (bq * LEN + wq) * DIM + chs;
        bSrc[rb] = (tile_n + rb * 64 + rd) * K_DIM + chs;
    }

    const int wave = tid >> 6, lane = tid & 63;
    const int wm = wave >> 2, wn = wave & 3;
    const int fr = lane & 15, kg = lane >> 4;
    const int sw    = (fr & 7) << 4;
    const int kOff0 = (kg * 16) ^ sw;
    const int kOff1 = kOff0 ^ 64;
    const int aRowB = (wm * 128 + fr) * 128;
    const int bRowB = (wn * 64 + fr) * 128;
    const int wOff  = wave * 1024;

    bh8 a0[4][2], fb0[2][2], fb1[2][2];
    f32x4 acc[8][4] = {};

    STG_A1(0, 0, 0); STG_A1(0, 0, 1); STG_A1(0, 0, 2); STG_A1(0, 0, 3);
    STG_B1(0, 0, 0); STG_B1(0, 0, 1); STG_B1(0, 0, 2); STG_B1(0, 0, 3);
    STG_A1(1, 1, 0); STG_A1(1, 1, 2);
    STG_B1(1, 1, 0); STG_B1(1, 1, 1);
    STG_A1(1, 1, 1); STG_A1(1, 1, 3);
    asm volatile("s_waitcnt vmcnt(6)" ::: "memory");
    __builtin_amdgcn_s_barrier();
    SB0;

#pragma unroll 1
    for (int it = 0; it < NITER; ++it) {
        const int b = 2 * it + 1;
        int c = 2 * it + 2; if (c >= NTILE) c = NTILE - 2;
        int d = 2 * it + 3; if (d >= NTILE) d = NTILE - 1;

        // ph0: rd B n01 + A mLo (buf0); stage b.Bu2,Bu3 -> buf1
        RD_B2(0, fb0, 0); RD_A4(0, 0);
        STG_B1(1, b, 2); STG_B1(1, b, 3);
        MFMA_Q(0, 0, fb0); PH_END;

        RD_B2(0, fb1, 2);
        STG_A1(0, c, 0); STG_A1(0, c, 2);
        MFMA_Q(0, 2, fb1); PH_END;

        RD_A4(0, 4);
        STG_B1(0, c, 0); STG_B1(0, c, 1);
        MFMA_Q(4, 2, fb1); PH_END;

        STG_A1(0, c, 1); STG_A1(0, c, 3);
        MFMA_Q(4, 0, fb0); PH_END_VM(6);

        // ph4-7: buf1 (tile b), prefetch d
        RD_B2(1, fb0, 0); RD_A4(1, 0);
        STG_B1(0, c, 2); STG_B1(0, c, 3);
        MFMA_Q(0, 0, fb0); PH_END;

        RD_B2(1, fb1, 2);
        STG_A1(1, d, 0); STG_A1(1, d, 2);
        MFMA_Q(0, 2, fb1); PH_END;

        RD_A4(1, 4);
        STG_B1(1, d, 0); STG_B1(1, d, 1);
        MFMA_Q(4, 2, fb1); PH_END;

        STG_A1(1, d, 1); STG_A1(1, d, 3);
        MFMA_Q(4, 0, fb0); PH_END_VM(6);
    }

    float bv[4];
    const float* bp = bias + tile_n + wn * 64 + fr;
#pragma unroll
    for (int ni = 0; ni < 4; ++ni) bv[ni] = bp[ni * 16];

    const int r0 = (lane >> 4) * 4;
#pragma unroll
    for (int mi = 0; mi < 8; ++mi) {
#pragma unroll
        for (int j = 0; j < 4; ++j) {
            long m = tile_m + wm * 128 + mi * 16 + r0 + j;
            float* crow = C + m * (long)N_DIM + tile_n + wn * 64 + fr;
#pragma unroll
            for (int ni = 0; ni < 4; ++ni)
                __builtin_nontemporal_store(acc[mi][ni][j] + bv[ni], &crow[ni * 16]);
        }
    }
}

// ============================ TAIL: 128x128, 16x16x32 ============================
#define TLDS_A(buf) (smem + (buf) * 32768)
#define TLDS_B(buf) (smem + (buf) * 32768 + 16384)

#define T_RD(buf) { \
    const char* _bb = TLDS_B(buf) + bRowB; \
    _Pragma("unroll") for (int ni = 0; ni < 2; ++ni) { \
        fb0[ni][0] = *(const bh8*)(_bb + ni * 2048 + kOff0); \
        fb0[ni][1] = *(const bh8*)(_bb + ni * 2048 + kOff1); \
    } \
    const char* _a = TLDS_A(buf) + aRowB; \
    _Pragma("unroll") for (int mi = 0; mi < 4; ++mi) { \
        a0[mi][0] = *(const bh8*)(_a + mi * 2048 + kOff0); \
        a0[mi][1] = *(const bh8*)(_a + mi * 2048 + kOff1); \
    } }
#define T_MFMA(MB) \
    _Pragma("unroll") for (int mi = 0; mi < 2; ++mi) \
    _Pragma("unroll") for (int ni = 0; ni < 2; ++ni) { \
        acc[MB + mi][ni] = __builtin_amdgcn_mfma_f32_16x16x32_bf16( \
            a0[MB + mi][0], fb0[ni][0], acc[MB + mi][ni], 0, 0, 0); \
        acc[MB + mi][ni] = __builtin_amdgcn_mfma_f32_16x16x32_bf16( \
            a0[MB + mi][1], fb0[ni][1], acc[MB + mi][ni], 0, 0, 0); \
    }
#define T_STG_A(buf, kt, u) \
    llds16(Ag + aSrc[u] + (kt) * 64, TLDS_A(buf) + (u) * 8192 + wOff);
#define T_STG_B(buf, kt, u) \
    llds16(Wg + bSrc[u] + (kt) * 64, TLDS_B(buf) + (u) * 8192 + wOff);

__global__ __launch_bounds__(512, 2)
void gemm_tail(const __hip_bfloat16* __restrict__ Ag,
               const __hip_bfloat16* __restrict__ Wg,
               const float* __restrict__ bias,
               float* __restrict__ C)
{
    extern __shared__ char smem[];

    const int tid = threadIdx.x;
    const int wgid = (blockIdx.x & 7) * (TAIL_WG / 8) + (blockIdx.x >> 3);
    const int qm = wgid / TAIL_QN;
    const int qn = wgid - qm * TAIL_QN;
    const int tile_m = TAIL_M0 + qm * 128;
    const int tile_n = qn * 128;

    const int rd  = tid >> 3;
    const int chs = (((tid & 7) ^ (rd & 7)) * 8);
    int aSrc[2], bSrc[2];
#pragma unroll
    for (int rb = 0; rb < 2; ++rb) {
        int m  = tile_m + rb * 64 + rd;
        int bq = m / NWIN;
        int wq = m - bq * NWIN;
        aSrc[rb] = (bq * LEN + wq) * DIM + chs;
        bSrc[rb] = (tile_n + rb * 64 + rd) * K_DIM + chs;
    }

    const int wave = tid >> 6, lane = tid & 63;
    const int wm = wave >> 2, wn = wave & 3;             // per-wave 64x32
    const int fr = lane & 15, kg = lane >> 4;
    const int sw    = (fr & 7) << 4;
    const int kOff0 = (kg * 16) ^ sw;
    const int kOff1 = kOff0 ^ 64;
    const int aRowB = (wm * 64 + fr) * 128;
    const int bRowB = (wn * 32 + fr) * 128;
    const int wOff  = wave * 1024;

    bh8 a0[4][2], fb0[2][2];
    f32x4 acc[4][2] = {};

    T_STG_A(0, 0, 0); T_STG_A(0, 0, 1); T_STG_B(0, 0, 0); T_STG_B(0, 0, 1);
    T_STG_A(1, 1, 0); T_STG_A(1, 1, 1);
    asm volatile("s_waitcnt vmcnt(2)" ::: "memory");
    __builtin_amdgcn_s_barrier();
    SB0;

#pragma unroll 1
    for (int it = 0; it < NITER; ++it) {
        const int b = 2 * it + 1;
        int c = 2 * it + 2; if (c >= NTILE) c = NTILE - 2;
        int d = 2 * it + 3; if (d >= NTILE) d = NTILE - 1;

        T_RD(0);
        T_STG_B(1, b, 0); T_STG_B(1, b, 1);
        T_MFMA(0); PH_END;

        T_STG_A(0, c, 0); T_STG_A(0, c, 1);
        T_MFMA(2); PH_END_VM(2);

        T_RD(1);
        T_STG_B(0, c, 0); T_STG_B(0, c, 1);
        T_MFMA(0); PH_END;

        T_STG_A(1, d, 0); T_STG_A(1, d, 1);
        T_MFMA(2); PH_END_VM(2);
    }

    float bv[2];
    const float* bp = bias + tile_n + wn * 32 + fr;
#pragma unroll
    for (int ni = 0; ni < 2; ++ni) bv[ni] = bp[ni * 16];

    const int r0 = (lane >> 4) * 4;
#pragma unroll
    for (int mi = 0; mi < 4; ++mi) {
#pragma unroll
        for (int j = 0; j < 4; ++j) {
            long m = tile_m + wm * 64 + mi * 16 + r0 + j;
            float* crow = C + m * (long)N_DIM + tile_n + wn * 32 + fr;
#pragma unroll
            for (int ni = 0; ni < 2; ++ni)
                __builtin_nontemporal_store(acc[mi][ni][j] + bv[ni], &crow[ni * 16]);
        }
    }
}

extern "C" void kernel_launch(void* const* d_in, const int* in_sizes, int n_in,
                              void* d_out, int out_size, void* d_ws, size_t ws_size,
                              hipStream_t stream) {
    const float* inp  = (const float*)d_in[0];
    const float* Wf   = (const float*)d_in[1];
    const float* bias = (const float*)d_in[2];
    float* out = (float*)d_out;

    __hip_bfloat16* Abf = (__hip_bfloat16*)d_ws;
    __hip_bfloat16* Wbf = (__hip_bfloat16*)((char*)d_ws + (size_t)BATCH * LEN * DIM * 2);

    const int nA8 = BATCH * LEN * DIM / 8;   // 589824
    const int nW8 = N_DIM * K_DIM / 8;       // 1179648
    const int nT8 = nA8 + nW8;
    cvt_both<<<(nT8 + 255) / 256, 256, 0, stream>>>(inp, Wf, Abf, Wbf, nA8, nT8);

    hipFuncSetAttribute((const void*)gemm_bulk,
                        hipFuncAttributeMaxDynamicSharedMemorySize, 131072);
    hipFuncSetAttribute((const void*)gemm_tail,
                        hipFuncAttributeMaxDynamicSharedMemorySize, 65536);
    gemm_bulk<<<dim3(BULK_WG), 512, 131072, stream>>>(Abf, Wbf, bias, out);
    gemm_tail<<<dim3(TAIL_WG), 512, 65536, stream>>>(Abf, Wbf, bias, out);
}